// Round 3
// baseline (2171.199 us; speedup 1.0000x reference)
//
#include <hip/hip_runtime.h>
#include <hip/hip_bf16.h>

using bf16 = __hip_bfloat16;

constexpr int BATCH = 32;
constexpr int INC = 3;
constexpr int OC = 64;
constexpr int HH = 64;
constexpr int WW = 64;
constexpr int KK = 5;
constexpr int HP = 32;
constexpr int WP = 32;
constexpr int NL = 16;
constexpr int LW = 128;
constexpr int OW = 100;

__device__ __forceinline__ float b2f(bf16 v) { return __bfloat162float(v); }

// ---------------- routing scores: conv(x, node_filter) -> global max ----------------
// grid: 4 depths * BATCH blocks, 256 threads
__global__ __launch_bounds__(256) void k_scores(
    const float* __restrict__ x, const float* __restrict__ nw,
    float* __restrict__ scores) {
  int d = blockIdx.x & 3;
  int b = blockIdx.x >> 2;
  int f = (2 << d) - 2;  // node filter index used at depth d: 0,2,6,14
  __shared__ float wsm[75];
  __shared__ float red[256];
  int t = threadIdx.x;
  if (t < 75) wsm[t] = nw[f * 75 + t];
  __syncthreads();
  float m = -3.0e38f;
  for (int p = t; p < HH * WW; p += 256) {
    int y = p >> 6, xx = p & 63;
    float s = 0.f;
    for (int ic = 0; ic < INC; ic++) {
      for (int ky = 0; ky < KK; ky++) {
        int yy = y + ky - 2;
        if (yy < 0 || yy >= HH) continue;
        const float* xr = x + ((b * INC + ic) * HH + yy) * WW;
        const float* wr = &wsm[(ic * KK + ky) * KK];
        for (int kx = 0; kx < KK; kx++) {
          int xc = xx + kx - 2;
          if (xc < 0 || xc >= WW) continue;
          s = fmaf(xr[xc], wr[kx], s);
        }
      }
    }
    m = fmaxf(m, s);
  }
  red[t] = m;
  __syncthreads();
  for (int s2 = 128; s2 > 0; s2 >>= 1) {
    if (t < s2) red[t] = fmaxf(red[t], red[t + s2]);
    __syncthreads();
  }
  if (t == 0) scores[d * BATCH + b] = red[0];
}

// ---------------- soft-routing mixture over the binary tree ----------------
// 1 block, BATCH*NL=512 threads
__global__ void k_mix(const float* __restrict__ scores,
                      const float* __restrict__ nb, float* __restrict__ mix) {
  int t = threadIdx.x;
  int b = t >> 4, l = t & 15;
  float m = 1.f;
#pragma unroll
  for (int d = 0; d < 4; d++) {
    int j = l >> (3 - d);
    int i = j >> 1;
    int bit = j & 1;
    float z = scores[d * BATCH + b] + nb[(1 << d) - 1 + i];
    float be = 1.f / (1.f + expf(-z));
    m *= bit ? be : (1.f - be);
  }
  mix[b * NL + l] = m;
}

// ---------------- conv1 (SAME,k5) + maxpool2 + relu -> h1 (bf16) ----------------
// grid: NL*BATCH*16 blocks (l, b, group-of-4 oc), 256 threads
__global__ __launch_bounds__(256) void k_conv1(
    const float* __restrict__ x, const float* __restrict__ cw1,
    bf16* __restrict__ h1) {
  constexpr int XR = 68;  // 64 + 2*2 zero pad rows
  constexpr int XP = 69;  // padded row stride (odd -> banks spread)
  __shared__ float xs[INC * XR * XP];
  __shared__ float wsm[4 * 75];
  int bid = blockIdx.x;
  int ocg = bid & 15;
  int b = (bid >> 4) & 31;
  int l = bid >> 9;
  int t = threadIdx.x;

  for (int i = t; i < INC * XR * XP; i += 256) {
    int ic = i / (XR * XP);
    int rem = i - ic * (XR * XP);
    int r = rem / XP, c = rem - r * XP;
    int yy = r - 2, xx = c - 2;
    float v = 0.f;
    if (yy >= 0 && yy < HH && xx >= 0 && xx < WW)
      v = x[((b * INC + ic) * HH + yy) * WW + xx];
    xs[i] = v;
  }
  for (int i = t; i < 300; i += 256) {
    int q = i / 75, r = i - q * 75;
    wsm[i] = cw1[(size_t)(l * OC + ocg * 4 + q) * 75 + r];
  }
  __syncthreads();

  float cv[4][4][4];  // [px-group i][oc q][pool pos]
#pragma unroll
  for (int i = 0; i < 4; i++)
#pragma unroll
    for (int q = 0; q < 4; q++)
#pragma unroll
      for (int p = 0; p < 4; p++) cv[i][q][p] = 0.f;

  int y0 = t >> 5, xx0 = t & 31;
  for (int ic = 0; ic < INC; ic++) {
#pragma unroll
    for (int ky = 0; ky < KK; ky++) {
      float wv[4][5];
#pragma unroll
      for (int q = 0; q < 4; q++)
#pragma unroll
        for (int kx = 0; kx < 5; kx++)
          wv[q][kx] = wsm[q * 75 + ic * 25 + ky * 5 + kx];
#pragma unroll
      for (int i = 0; i < 4; i++) {
        int y = y0 + 8 * i;
        const float* r0 = &xs[(ic * XR + (2 * y + ky)) * XP + 2 * xx0];
        float a0[6], a1[6];
#pragma unroll
        for (int c = 0; c < 6; c++) {
          a0[c] = r0[c];
          a1[c] = r0[XP + c];
        }
#pragma unroll
        for (int kx = 0; kx < 5; kx++) {
#pragma unroll
          for (int q = 0; q < 4; q++) {
            float w = wv[q][kx];
            cv[i][q][0] = fmaf(a0[kx], w, cv[i][q][0]);
            cv[i][q][1] = fmaf(a0[kx + 1], w, cv[i][q][1]);
            cv[i][q][2] = fmaf(a1[kx], w, cv[i][q][2]);
            cv[i][q][3] = fmaf(a1[kx + 1], w, cv[i][q][3]);
          }
        }
      }
    }
  }
#pragma unroll
  for (int i = 0; i < 4; i++) {
    int y = y0 + 8 * i;
#pragma unroll
    for (int q = 0; q < 4; q++) {
      float v = fmaxf(fmaxf(cv[i][q][0], cv[i][q][1]),
                      fmaxf(cv[i][q][2], cv[i][q][3]));
      v = fmaxf(v, 0.f);
      h1[((size_t)(l * BATCH + b) * OC + (ocg * 4 + q)) * (HP * WP) + y * WP + xx0] =
          __float2bfloat16(v);
    }
  }
}

// ---------------- conv2 (SAME,k5) + relu + global spatial max -> feat ----------------
// grid: NL*BATCH*8 blocks (l, b, group-of-8 oc), 256 threads
__global__ __launch_bounds__(256) void k_conv2(
    const bf16* __restrict__ h1, const float* __restrict__ cw2,
    float* __restrict__ feat) {
  constexpr int HS = 37;  // padded stride: (5*row + 8*xseg + c) mod 32 -> <=2-way (free)
  __shared__ float hs[36 * HS];
  __shared__ float wsm[8 * 25];
  __shared__ float red[8 * 128];
  int bid = blockIdx.x;
  int ocg = bid & 7;
  int b = (bid >> 3) & 31;
  int l = bid >> 8;
  int t = threadIdx.x;
  int osub = t >> 7;       // which 4-oc half
  int g = t & 127;         // 128 pixel groups
  int row = g >> 2;
  int xb = (g & 3) * 8;

  float acc[4][8];
#pragma unroll
  for (int q = 0; q < 4; q++)
#pragma unroll
    for (int j = 0; j < 8; j++) acc[q][j] = 0.f;

  const bf16* h1base = h1 + (size_t)(l * BATCH + b) * OC * (HP * WP);
  const float* wbase = cw2 + (size_t)(l * OC + ocg * 8) * OC * 25;

  for (int ic = 0; ic < OC; ic++) {
    __syncthreads();
    const bf16* hp = h1base + ic * (HP * WP);
    for (int i = t; i < 36 * HS; i += 256) {
      int r = i / HS, c = i - r * HS;
      int yy = r - 2, xx = c - 2;
      float v = 0.f;
      if (yy >= 0 && yy < HP && xx >= 0 && xx < WP) v = b2f(hp[yy * WP + xx]);
      hs[i] = v;
    }
    if (t < 200) {
      int j = t / 25, k = t - j * 25;
      wsm[t] = wbase[(j * OC + ic) * 25 + k];
    }
    __syncthreads();
#pragma unroll
    for (int ky = 0; ky < KK; ky++) {
      float a[12];
      const float* hr = &hs[(row + ky) * HS + xb];
#pragma unroll
      for (int c = 0; c < 12; c++) a[c] = hr[c];
#pragma unroll
      for (int kx = 0; kx < KK; kx++) {
#pragma unroll
        for (int q = 0; q < 4; q++) {
          float w = wsm[(osub * 4 + q) * 25 + ky * 5 + kx];
#pragma unroll
          for (int j = 0; j < 8; j++) acc[q][j] = fmaf(a[kx + j], w, acc[q][j]);
        }
      }
    }
  }
  __syncthreads();
#pragma unroll
  for (int q = 0; q < 4; q++) {
    float m = acc[q][0];
#pragma unroll
    for (int j = 1; j < 8; j++) m = fmaxf(m, acc[q][j]);
    red[(osub * 4 + q) * 128 + g] = m;
  }
  __syncthreads();
  if (t < 8) {
    const float* rr = &red[t * 128];
    float m = rr[0];
    for (int i = 1; i < 128; i++) m = fmaxf(m, rr[i]);
    feat[(size_t)(l * BATCH + b) * OC + ocg * 8 + t] = fmaxf(m, 0.f);  // relu(max)=max(relu)
  }
}

// ---------------- per-leaf 2-layer MLP (no activation between, per reference) ----------------
// grid: NL*BATCH blocks, 128 threads
__global__ __launch_bounds__(128) void k_mlp(
    const float* __restrict__ feat, const float* __restrict__ w1s,
    const float* __restrict__ b1s, const float* __restrict__ w2s,
    const float* __restrict__ b2s, float* __restrict__ logits) {
  __shared__ float fs[OC];
  __shared__ float hid[LW];
  int bid = blockIdx.x;
  int b = bid & 31;
  int l = bid >> 5;
  int t = threadIdx.x;
  if (t < OC) fs[t] = feat[(size_t)(l * BATCH + b) * OC + t];
  __syncthreads();
  float h = b1s[l * LW + t];
  for (int c = 0; c < OC; c++)
    h = fmaf(fs[c], w1s[(l * OC + c) * LW + t], h);
  hid[t] = h;
  __syncthreads();
  if (t < OW) {
    float o = b2s[l * OW + t];
    for (int j = 0; j < LW; j++)
      o = fmaf(hid[j], w2s[(l * LW + j) * OW + t], o);
    logits[(size_t)(l * BATCH + b) * OW + t] = o;
  }
}

// ---------------- out[b,o] = sum_l mix[b,l] * logits[l,b,o] ----------------
// OUTPUT IS FP32 (R2 post-mortem: bf16 write produced exactly the pair-shuffle
// error signature of an fp32 reader on a half-filled buffer).
__global__ __launch_bounds__(256) void k_combine(
    const float* __restrict__ logits, const float* __restrict__ mix,
    float* __restrict__ out) {
  int idx = blockIdx.x * 256 + threadIdx.x;
  if (idx >= BATCH * OW) return;
  int b = idx / OW, o = idx - b * OW;
  float s = 0.f;
#pragma unroll
  for (int l = 0; l < NL; l++)
    s = fmaf(mix[b * NL + l], logits[((size_t)l * BATCH + b) * OW + o], s);
  out[idx] = s;
}

extern "C" void kernel_launch(void* const* d_in, const int* in_sizes, int n_in,
                              void* d_out, int out_size, void* d_ws, size_t ws_size,
                              hipStream_t stream) {
  const float* x   = (const float*)d_in[0];
  const float* nw  = (const float*)d_in[1];
  const float* nb  = (const float*)d_in[2];
  const float* cw1 = (const float*)d_in[3];
  const float* cw2 = (const float*)d_in[4];
  const float* w1s = (const float*)d_in[5];
  const float* b1s = (const float*)d_in[6];
  const float* w2s = (const float*)d_in[7];
  const float* b2s = (const float*)d_in[8];
  float* out = (float*)d_out;

  char* ws = (char*)d_ws;
  bf16* h1 = (bf16*)ws;  // NL*BATCH*OC*32*32 bf16 = 64 MiB
  size_t off = (size_t)NL * BATCH * OC * HP * WP * sizeof(bf16);
  float* scores = (float*)(ws + off); off += 4 * BATCH * sizeof(float);
  float* mixp   = (float*)(ws + off); off += BATCH * NL * sizeof(float);
  float* feat   = (float*)(ws + off); off += (size_t)NL * BATCH * OC * sizeof(float);
  float* logits = (float*)(ws + off); off += (size_t)NL * BATCH * OW * sizeof(float);
  (void)ws_size; (void)in_sizes; (void)n_in; (void)out_size;

  k_scores<<<4 * BATCH, 256, 0, stream>>>(x, nw, scores);
  k_mix<<<1, BATCH * NL, 0, stream>>>(scores, nb, mixp);
  k_conv1<<<NL * BATCH * 16, 256, 0, stream>>>(x, cw1, h1);
  k_conv2<<<NL * BATCH * 8, 256, 0, stream>>>(h1, cw2, feat);
  k_mlp<<<NL * BATCH, 128, 0, stream>>>(feat, w1s, b1s, w2s, b2s, logits);
  k_combine<<<(BATCH * OW + 255) / 256, 256, 0, stream>>>(logits, mixp, out);
}

// Round 4
// 1227.753 us; speedup vs baseline: 1.7684x; 1.7684x over previous
//
#include <hip/hip_runtime.h>
#include <hip/hip_bf16.h>

using bf16 = __hip_bfloat16;
typedef __attribute__((ext_vector_type(8))) short short8;   // 8 bf16 (4 VGPR)
typedef __attribute__((ext_vector_type(4))) short short4v;  // 4 bf16 (8 B)
typedef __attribute__((ext_vector_type(4))) float f32x4;

constexpr int BATCH = 32;
constexpr int INC = 3;
constexpr int OC = 64;
constexpr int HH = 64;
constexpr int WW = 64;
constexpr int KK = 5;
constexpr int HP = 32;
constexpr int WP = 32;
constexpr int NL = 16;
constexpr int LW = 128;
constexpr int OW = 100;

__device__ __forceinline__ float b2f(bf16 v) { return __bfloat162float(v); }
__device__ __forceinline__ short f2bs(float v) {
  bf16 h = __float2bfloat16(v);
  return *(short*)&h;
}

// ---------------- routing scores: conv(x, node_filter) -> global max ----------------
__global__ __launch_bounds__(256) void k_scores(
    const float* __restrict__ x, const float* __restrict__ nw,
    float* __restrict__ scores) {
  int d = blockIdx.x & 3;
  int b = blockIdx.x >> 2;
  int f = (2 << d) - 2;  // node filter index used at depth d: 0,2,6,14
  __shared__ float wsm[75];
  __shared__ float red[256];
  int t = threadIdx.x;
  if (t < 75) wsm[t] = nw[f * 75 + t];
  __syncthreads();
  float m = -3.0e38f;
  for (int p = t; p < HH * WW; p += 256) {
    int y = p >> 6, xx = p & 63;
    float s = 0.f;
    for (int ic = 0; ic < INC; ic++) {
      for (int ky = 0; ky < KK; ky++) {
        int yy = y + ky - 2;
        if (yy < 0 || yy >= HH) continue;
        const float* xr = x + ((b * INC + ic) * HH + yy) * WW;
        const float* wr = &wsm[(ic * KK + ky) * KK];
        for (int kx = 0; kx < KK; kx++) {
          int xc = xx + kx - 2;
          if (xc < 0 || xc >= WW) continue;
          s = fmaf(xr[xc], wr[kx], s);
        }
      }
    }
    m = fmaxf(m, s);
  }
  red[t] = m;
  __syncthreads();
  for (int s2 = 128; s2 > 0; s2 >>= 1) {
    if (t < s2) red[t] = fmaxf(red[t], red[t + s2]);
    __syncthreads();
  }
  if (t == 0) scores[d * BATCH + b] = red[0];
}

// ---------------- soft-routing mixture over the binary tree ----------------
__global__ void k_mix(const float* __restrict__ scores,
                      const float* __restrict__ nb, float* __restrict__ mix) {
  int t = threadIdx.x;
  int b = t >> 4, l = t & 15;
  float m = 1.f;
#pragma unroll
  for (int d = 0; d < 4; d++) {
    int j = l >> (3 - d);
    int i = j >> 1;
    int bit = j & 1;
    float z = scores[d * BATCH + b] + nb[(1 << d) - 1 + i];
    float be = 1.f / (1.f + expf(-z));
    m *= bit ? be : (1.f - be);
  }
  mix[b * NL + l] = m;
}

// ---------------- conv1 (SAME,k5) + maxpool2 + relu -> h1t [l,b][y][x][ic] bf16 ----------------
// grid: NL*BATCH*16 blocks (l, b, group-of-4 oc), 256 threads
__global__ __launch_bounds__(256) void k_conv1(
    const float* __restrict__ x, const float* __restrict__ cw1,
    short* __restrict__ h1t) {
  constexpr int XR = 68;
  constexpr int XP = 69;
  __shared__ float xs[INC * XR * XP];
  __shared__ float wsm[4 * 75];
  int bid = blockIdx.x;
  int ocg = bid & 15;
  int b = (bid >> 4) & 31;
  int l = bid >> 9;
  int t = threadIdx.x;

  for (int i = t; i < INC * XR * XP; i += 256) {
    int ic = i / (XR * XP);
    int rem = i - ic * (XR * XP);
    int r = rem / XP, c = rem - r * XP;
    int yy = r - 2, xx = c - 2;
    float v = 0.f;
    if (yy >= 0 && yy < HH && xx >= 0 && xx < WW)
      v = x[((b * INC + ic) * HH + yy) * WW + xx];
    xs[i] = v;
  }
  for (int i = t; i < 300; i += 256) {
    int q = i / 75, r = i - q * 75;
    wsm[i] = cw1[(size_t)(l * OC + ocg * 4 + q) * 75 + r];
  }
  __syncthreads();

  float cv[4][4][4];
#pragma unroll
  for (int i = 0; i < 4; i++)
#pragma unroll
    for (int q = 0; q < 4; q++)
#pragma unroll
      for (int p = 0; p < 4; p++) cv[i][q][p] = 0.f;

  int y0 = t >> 5, xx0 = t & 31;
  for (int ic = 0; ic < INC; ic++) {
#pragma unroll
    for (int ky = 0; ky < KK; ky++) {
      float wv[4][5];
#pragma unroll
      for (int q = 0; q < 4; q++)
#pragma unroll
        for (int kx = 0; kx < 5; kx++)
          wv[q][kx] = wsm[q * 75 + ic * 25 + ky * 5 + kx];
#pragma unroll
      for (int i = 0; i < 4; i++) {
        int y = y0 + 8 * i;
        const float* r0 = &xs[(ic * XR + (2 * y + ky)) * XP + 2 * xx0];
        float a0[6], a1[6];
#pragma unroll
        for (int c = 0; c < 6; c++) {
          a0[c] = r0[c];
          a1[c] = r0[XP + c];
        }
#pragma unroll
        for (int kx = 0; kx < 5; kx++) {
#pragma unroll
          for (int q = 0; q < 4; q++) {
            float w = wv[q][kx];
            cv[i][q][0] = fmaf(a0[kx], w, cv[i][q][0]);
            cv[i][q][1] = fmaf(a0[kx + 1], w, cv[i][q][1]);
            cv[i][q][2] = fmaf(a1[kx], w, cv[i][q][2]);
            cv[i][q][3] = fmaf(a1[kx + 1], w, cv[i][q][3]);
          }
        }
      }
    }
  }
#pragma unroll
  for (int i = 0; i < 4; i++) {
    int y = y0 + 8 * i;
    short4v sv;
#pragma unroll
    for (int q = 0; q < 4; q++) {
      float v = fmaxf(fmaxf(cv[i][q][0], cv[i][q][1]),
                      fmaxf(cv[i][q][2], cv[i][q][3]));
      sv[q] = f2bs(fmaxf(v, 0.f));
    }
    *(short4v*)(h1t + ((size_t)(l * BATCH + b) * (HP * WP) + y * WP + xx0) * OC + ocg * 4) = sv;
  }
}

// ---------------- weight prep: cw2[l][oc][ic][5][5] fp32 -> wT[l][tap][oc][ic] bf16 ----------
// grid: 800 blocks * 256 threads, each thread 8 ic
__global__ __launch_bounds__(256) void k_wprep(const float* __restrict__ cw2,
                                               short* __restrict__ wT) {
  int idx = blockIdx.x * 256 + threadIdx.x;  // 204800
  int icq = idx & 7;
  int oc = (idx >> 3) & 63;
  int rem = idx >> 9;  // l*25 + tap
  short8 v;
#pragma unroll
  for (int j = 0; j < 8; j++) {
    int ic = icq * 8 + j;
    int l = rem / 25, tap = rem % 25;
    v[j] = f2bs(cw2[((size_t)(l * OC + oc) * OC + ic) * 25 + tap]);
  }
  *(short8*)(wT + ((size_t)rem * OC + oc) * OC + icq * 8) = v;
}

// ---------------- conv2 via MFMA implicit GEMM + spatial max -> pfeat ----------------
// grid: NL*BATCH*4 blocks (l, b, 8-row stripe), 256 threads = 4 waves
// wave w: out rows {2w, 2w+1} (local), all 64 oc. 16x16x32 bf16 MFMA.
__global__ __launch_bounds__(256) void k_conv2m(
    const short* __restrict__ h1t, const short* __restrict__ wT,
    float* __restrict__ pfeat) {
  constexpr int CS = 72;        // ic slot stride (64 + 8 pad): 16B-aligned, <=2-way banks
  constexpr int RS = 36 * CS;   // row stride (elems)
  __shared__ alignas(16) short hs[12 * 36 * CS];  // 62208 B
  __shared__ alignas(16) float sred[4][64];
  int bid = blockIdx.x;
  int stripe = bid & 3;
  int b = (bid >> 2) & 31;
  int l = bid >> 7;
  int t = threadIdx.x;
  int w = t >> 6, lane = t & 63;
  int n = lane & 15, q = lane >> 4;

  // zero LDS (halo stays zero), then stage interior rows once
  for (int i = t; i < 12 * 36 * CS / 2; i += 256) ((int*)hs)[i] = 0;
  __syncthreads();
  int y0 = stripe * 8;
  const short* hg = h1t + (size_t)(l * BATCH + b) * (HP * WP) * OC;
  {
    int col = t >> 3, icq = t & 7;
    for (int r = 0; r < 12; r++) {
      int y = y0 - 2 + r;
      if (y < 0 || y >= HP) continue;
      short8 v = *(const short8*)(hg + (y * WP + col) * OC + icq * 8);
      *(short8*)(&hs[r * RS + (col + 2) * CS + icq * 8]) = v;
    }
  }
  __syncthreads();

  f32x4 acc[4][4];  // [octile][pxtile]
#pragma unroll
  for (int i = 0; i < 4; i++)
#pragma unroll
    for (int j = 0; j < 4; j++) acc[i][j] = f32x4{0.f, 0.f, 0.f, 0.f};

  const short* wbase = wT + (size_t)l * 25 * OC * OC;
  short8 Acur[8], Anext[8];
  // A-frag: A[m=lane&15][k=q*8+j] ; m=oc within tile, k=ic within 32-slice
#pragma unroll
  for (int oct = 0; oct < 4; oct++)
#pragma unroll
    for (int kk = 0; kk < 2; kk++)
      Anext[oct * 2 + kk] =
          *(const short8*)(wbase + (size_t)(oct * 16 + n) * OC + kk * 32 + q * 8);

  int prow = 2 * w;
  for (int tap = 0; tap < 25; tap++) {
#pragma unroll
    for (int i = 0; i < 8; i++) Acur[i] = Anext[i];
    if (tap < 24) {
      const short* tb = wbase + (size_t)(tap + 1) * OC * OC;
#pragma unroll
      for (int oct = 0; oct < 4; oct++)
#pragma unroll
        for (int kk = 0; kk < 2; kk++)
          Anext[oct * 2 + kk] =
              *(const short8*)(tb + (size_t)(oct * 16 + n) * OC + kk * 32 + q * 8);
    }
    int dy = tap / 5, dx = tap - 5 * dy;
#pragma unroll
    for (int pxt = 0; pxt < 4; pxt++) {
      int r = prow + (pxt >> 1) + dy;
      int c = (pxt & 1) * 16 + n + dx;
      const short* bp = &hs[r * RS + c * CS];
#pragma unroll
      for (int kk = 0; kk < 2; kk++) {
        short8 B = *(const short8*)(bp + kk * 32 + q * 8);  // B[k=q*8+j][n=lane&15]
#pragma unroll
        for (int oct = 0; oct < 4; oct++)
          acc[oct][pxt] = __builtin_amdgcn_mfma_f32_16x16x32_bf16(
              Acur[oct * 2 + kk], B, acc[oct][pxt], 0, 0, 0);
      }
    }
  }

  // epilogue: max over this wave's 64 px; D layout: col(px)=lane&15, row(oc)=q*4+reg
#pragma unroll
  for (int oct = 0; oct < 4; oct++) {
    f32x4 m = acc[oct][0];
#pragma unroll
    for (int pxt = 1; pxt < 4; pxt++)
#pragma unroll
      for (int r = 0; r < 4; r++) m[r] = fmaxf(m[r], acc[oct][pxt][r]);
#pragma unroll
    for (int mask = 1; mask <= 8; mask <<= 1)
#pragma unroll
      for (int r = 0; r < 4; r++) m[r] = fmaxf(m[r], __shfl_xor(m[r], mask, 64));
    if (n == 0) *(f32x4*)&sred[w][oct * 16 + q * 4] = m;
  }
  __syncthreads();
  if (t < 64) {
    float m = fmaxf(fmaxf(sred[0][t], sred[1][t]), fmaxf(sred[2][t], sred[3][t]));
    pfeat[((size_t)(l * BATCH + b) * 4 + stripe) * OC + t] = m;
  }
}

// ---------------- per-leaf 2-layer MLP; folds stripe-max + relu ----------------
__global__ __launch_bounds__(128) void k_mlp(
    const float* __restrict__ pfeat, const float* __restrict__ w1s,
    const float* __restrict__ b1s, const float* __restrict__ w2s,
    const float* __restrict__ b2s, float* __restrict__ logits) {
  __shared__ float fs[OC];
  __shared__ float hid[LW];
  int bid = blockIdx.x;
  int b = bid & 31;
  int l = bid >> 5;
  int t = threadIdx.x;
  if (t < OC) {
    const float* pf = pfeat + (size_t)(l * BATCH + b) * 4 * OC;
    float m = fmaxf(fmaxf(pf[t], pf[OC + t]), fmaxf(pf[2 * OC + t], pf[3 * OC + t]));
    fs[t] = fmaxf(m, 0.f);  // relu(global max)
  }
  __syncthreads();
  float h = b1s[l * LW + t];
  for (int c = 0; c < OC; c++)
    h = fmaf(fs[c], w1s[(l * OC + c) * LW + t], h);
  hid[t] = h;
  __syncthreads();
  if (t < OW) {
    float o = b2s[l * OW + t];
    for (int j = 0; j < LW; j++)
      o = fmaf(hid[j], w2s[(l * LW + j) * OW + t], o);
    logits[(size_t)(l * BATCH + b) * OW + t] = o;
  }
}

// ---------------- out[b,o] = sum_l mix[b,l] * logits[l,b,o]  (fp32 out) ----------------
__global__ __launch_bounds__(256) void k_combine(
    const float* __restrict__ logits, const float* __restrict__ mix,
    float* __restrict__ out) {
  int idx = blockIdx.x * 256 + threadIdx.x;
  if (idx >= BATCH * OW) return;
  int b = idx / OW, o = idx - b * OW;
  float s = 0.f;
#pragma unroll
  for (int l = 0; l < NL; l++)
    s = fmaf(mix[b * NL + l], logits[((size_t)l * BATCH + b) * OW + o], s);
  out[idx] = s;
}

extern "C" void kernel_launch(void* const* d_in, const int* in_sizes, int n_in,
                              void* d_out, int out_size, void* d_ws, size_t ws_size,
                              hipStream_t stream) {
  const float* x   = (const float*)d_in[0];
  const float* nw  = (const float*)d_in[1];
  const float* nb  = (const float*)d_in[2];
  const float* cw1 = (const float*)d_in[3];
  const float* cw2 = (const float*)d_in[4];
  const float* w1s = (const float*)d_in[5];
  const float* b1s = (const float*)d_in[6];
  const float* w2s = (const float*)d_in[7];
  const float* b2s = (const float*)d_in[8];
  float* out = (float*)d_out;

  char* ws = (char*)d_ws;
  short* h1t = (short*)ws;  // [l,b][px 1024][ic 64] bf16 = 67.1 MB
  size_t off = (size_t)NL * BATCH * HP * WP * OC * sizeof(short);
  short* wT = (short*)(ws + off); off += (size_t)NL * 25 * OC * OC * sizeof(short);  // 3.28 MB
  float* scores = (float*)(ws + off); off += 4 * BATCH * sizeof(float);
  float* mixp   = (float*)(ws + off); off += BATCH * NL * sizeof(float);
  float* pfeat  = (float*)(ws + off); off += (size_t)NL * BATCH * 4 * OC * sizeof(float);
  float* logits = (float*)(ws + off); off += (size_t)NL * BATCH * OW * sizeof(float);
  (void)ws_size; (void)in_sizes; (void)n_in; (void)out_size;

  k_scores<<<4 * BATCH, 256, 0, stream>>>(x, nw, scores);
  k_mix<<<1, BATCH * NL, 0, stream>>>(scores, nb, mixp);
  k_conv1<<<NL * BATCH * 16, 256, 0, stream>>>(x, cw1, h1t);
  k_wprep<<<NL * 25 * OC * 8 / 256, 256, 0, stream>>>(cw2, wT);
  k_conv2m<<<NL * BATCH * 4, 256, 0, stream>>>(h1t, wT, pfeat);
  k_mlp<<<NL * BATCH, 128, 0, stream>>>(pfeat, w1s, b1s, w2s, b2s, logits);
  k_combine<<<(BATCH * OW + 255) / 256, 256, 0, stream>>>(logits, mixp, out);
}

// Round 5
// 446.459 us; speedup vs baseline: 4.8632x; 2.7500x over previous
//
#include <hip/hip_runtime.h>
#include <hip/hip_bf16.h>

using bf16 = __hip_bfloat16;
typedef __attribute__((ext_vector_type(8))) short short8;   // 8 bf16 (4 VGPR)
typedef __attribute__((ext_vector_type(4))) short short4v;  // 4 bf16 (8 B)
typedef __attribute__((ext_vector_type(4))) float f32x4;

constexpr int BATCH = 32;
constexpr int INC = 3;
constexpr int OC = 64;
constexpr int HH = 64;
constexpr int WW = 64;
constexpr int KK = 5;
constexpr int HP = 32;
constexpr int WP = 32;
constexpr int NL = 16;
constexpr int LW = 128;
constexpr int OW = 100;

__device__ __forceinline__ float b2f(bf16 v) { return __bfloat162float(v); }
__device__ __forceinline__ short f2bs(float v) {
  bf16 h = __float2bfloat16(v);
  return *(short*)&h;
}

// ---------------- routing scores: conv(x, node_filter) -> global max ----------------
__global__ __launch_bounds__(256) void k_scores(
    const float* __restrict__ x, const float* __restrict__ nw,
    float* __restrict__ scores) {
  int d = blockIdx.x & 3;
  int b = blockIdx.x >> 2;
  int f = (2 << d) - 2;  // node filter index used at depth d: 0,2,6,14
  __shared__ float wsm[75];
  __shared__ float red[256];
  int t = threadIdx.x;
  if (t < 75) wsm[t] = nw[f * 75 + t];
  __syncthreads();
  float m = -3.0e38f;
  for (int p = t; p < HH * WW; p += 256) {
    int y = p >> 6, xx = p & 63;
    float s = 0.f;
    for (int ic = 0; ic < INC; ic++) {
      for (int ky = 0; ky < KK; ky++) {
        int yy = y + ky - 2;
        if (yy < 0 || yy >= HH) continue;
        const float* xr = x + ((b * INC + ic) * HH + yy) * WW;
        const float* wr = &wsm[(ic * KK + ky) * KK];
        for (int kx = 0; kx < KK; kx++) {
          int xc = xx + kx - 2;
          if (xc < 0 || xc >= WW) continue;
          s = fmaf(xr[xc], wr[kx], s);
        }
      }
    }
    m = fmaxf(m, s);
  }
  red[t] = m;
  __syncthreads();
  for (int s2 = 128; s2 > 0; s2 >>= 1) {
    if (t < s2) red[t] = fmaxf(red[t], red[t + s2]);
    __syncthreads();
  }
  if (t == 0) scores[d * BATCH + b] = red[0];
}

// ---------------- soft-routing mixture over the binary tree ----------------
__global__ void k_mix(const float* __restrict__ scores,
                      const float* __restrict__ nb, float* __restrict__ mix) {
  int t = threadIdx.x;
  int b = t >> 4, l = t & 15;
  float m = 1.f;
#pragma unroll
  for (int d = 0; d < 4; d++) {
    int j = l >> (3 - d);
    int i = j >> 1;
    int bit = j & 1;
    float z = scores[d * BATCH + b] + nb[(1 << d) - 1 + i];
    float be = 1.f / (1.f + expf(-z));
    m *= bit ? be : (1.f - be);
  }
  mix[b * NL + l] = m;
}

// ---------------- weight prep conv1: cw1[l*64+oc][75] fp32 -> wA[l][oc][96] bf16 (zero-pad) --
__global__ __launch_bounds__(256) void k_w1prep(const float* __restrict__ cw1,
                                                short* __restrict__ wA) {
  int idx = blockIdx.x * 256 + threadIdx.x;  // 16*64*96 = 98304
  int k = idx % 96;
  int rem = idx / 96;  // l*64 + oc
  float v = (k < 75) ? cw1[(size_t)rem * 75 + k] : 0.f;
  wA[(size_t)rem * 96 + k] = f2bs(v);
}

// ---------------- conv1 via im2col + MFMA + in-register maxpool/relu -> h1t ----------------
// grid: BATCH*32 blocks (b, pool-row py), 256 threads = 4 waves (wave = 16-oc group)
// Bm LDS layout: [dy][col][k(96 pad)] bf16, per-col 16B bank-rotation so quarter-wave
// B-frag reads are <=2-way (free). Built once, reused by all 16 leaves, no l-loop barriers.
__device__ __forceinline__ int slotbase(int col) {
  return col * 104 + 8 * ((-(col >> 1)) & 7);
}

__global__ __launch_bounds__(256) void k_conv1m(
    const float* __restrict__ x, const short* __restrict__ wA,
    short* __restrict__ h1t) {
  constexpr int BSZ = 64 * 104 + 64;  // per-dy slab size in shorts (incl. rotation slack)
  __shared__ alignas(16) short Bm[2 * BSZ];
  int bid = blockIdx.x;
  int py = bid & 31;
  int b = bid >> 5;
  int t = threadIdx.x;
  int w = t >> 6, lane = t & 63;
  int n = lane & 15, q = lane >> 4;

  // zero the slab (covers k-pad 75..95 and rotation gaps; A is zero there anyway)
  for (int i = t; i < BSZ; i += 256) ((int*)Bm)[i] = 0;
  __syncthreads();
  // im2col build: Bm[dy][c][k] = x[b][ic][2py+dy+ky-2][c+kx-2], k=(ic,ky,kx)
  for (int i = t; i < 1200; i += 256) {
    int cg = i & 7;
    int kk = (i >> 3) % 75;
    int dy = (i >> 3) / 75;
    int ic = kk / 25, r25 = kk % 25;
    int ky = r25 / 5, kx = r25 % 5;
    int y = 2 * py + dy + ky - 2;
    const float* xr = x + ((size_t)(b * INC + ic) * HH + y) * WW;
    short* dst = Bm + dy * BSZ;
#pragma unroll
    for (int c8 = 0; c8 < 8; c8++) {
      int c = cg * 8 + c8;
      int cx = c + kx - 2;
      float v = 0.f;
      if (y >= 0 && y < HH && cx >= 0 && cx < WW) v = xr[cx];
      dst[slotbase(c) + kk] = f2bs(v);
    }
  }
  __syncthreads();

  // A-frag: A[m=lane&15][k=q*8+j], m=oc within 16-tile; prefetch next l during MFMA
  short8 Acur[3], Anx[3];
#pragma unroll
  for (int ks = 0; ks < 3; ks++)
    Anx[ks] = *(const short8*)(wA + ((size_t)(w * 16 + n) * 96) + ks * 32 + q * 8);

  for (int l = 0; l < NL; l++) {
#pragma unroll
    for (int ks = 0; ks < 3; ks++) Acur[ks] = Anx[ks];
    if (l < NL - 1) {
#pragma unroll
      for (int ks = 0; ks < 3; ks++)
        Anx[ks] = *(const short8*)(wA + ((size_t)((l + 1) * OC + w * 16 + n) * 96) +
                                   ks * 32 + q * 8);
    }
    f32x4 acc[2][2][2];  // [dy][dx][half]
#pragma unroll
    for (int dy = 0; dy < 2; dy++)
#pragma unroll
      for (int dx = 0; dx < 2; dx++)
#pragma unroll
        for (int h = 0; h < 2; h++) acc[dy][dx][h] = f32x4{0.f, 0.f, 0.f, 0.f};

#pragma unroll
    for (int dy = 0; dy < 2; dy++)
#pragma unroll
      for (int dx = 0; dx < 2; dx++)
#pragma unroll
        for (int h = 0; h < 2; h++) {
          int col = 2 * (h * 16 + n) + dx;
          const short* bp = Bm + dy * BSZ + slotbase(col);
#pragma unroll
          for (int ks = 0; ks < 3; ks++) {
            short8 Bf = *(const short8*)(bp + ks * 32 + q * 8);
            acc[dy][dx][h] = __builtin_amdgcn_mfma_f32_16x16x32_bf16(
                Acur[ks], Bf, acc[dy][dx][h], 0, 0, 0);
          }
        }

    // pool over (dy,dx), relu, write. D layout: col(px)=lane&15, row(oc)=q*4+reg.
#pragma unroll
    for (int h = 0; h < 2; h++) {
      short4v sv;
#pragma unroll
      for (int r = 0; r < 4; r++) {
        float v = fmaxf(fmaxf(acc[0][0][h][r], acc[0][1][h][r]),
                        fmaxf(acc[1][0][h][r], acc[1][1][h][r]));
        sv[r] = f2bs(fmaxf(v, 0.f));
      }
      int px = py * WP + h * 16 + n;
      *(short4v*)(h1t + ((size_t)(l * BATCH + b) * (HP * WP) + px) * OC + w * 16 + q * 4) = sv;
    }
  }
}

// ---------------- weight prep conv2: cw2[l][oc][ic][5][5] fp32 -> wT[l][tap][oc][ic] bf16 ----
__global__ __launch_bounds__(256) void k_wprep(const float* __restrict__ cw2,
                                               short* __restrict__ wT) {
  int idx = blockIdx.x * 256 + threadIdx.x;  // 204800
  int icq = idx & 7;
  int oc = (idx >> 3) & 63;
  int rem = idx >> 9;  // l*25 + tap
  short8 v;
#pragma unroll
  for (int j = 0; j < 8; j++) {
    int ic = icq * 8 + j;
    int l = rem / 25, tap = rem % 25;
    v[j] = f2bs(cw2[((size_t)(l * OC + oc) * OC + ic) * 25 + tap]);
  }
  *(short8*)(wT + ((size_t)rem * OC + oc) * OC + icq * 8) = v;
}

// ---------------- conv2 via MFMA implicit GEMM + spatial max -> pfeat ----------------
// grid: NL*BATCH*4 blocks (l, b, 8-row stripe), 256 threads = 4 waves
__global__ __launch_bounds__(256) void k_conv2m(
    const short* __restrict__ h1t, const short* __restrict__ wT,
    float* __restrict__ pfeat) {
  constexpr int CS = 72;        // ic slot stride (64 + 8 pad): 16B-aligned, <=2-way banks
  constexpr int RS = 36 * CS;   // row stride (elems)
  __shared__ alignas(16) short hs[12 * 36 * CS];  // 62208 B
  __shared__ alignas(16) float sred[4][64];
  int bid = blockIdx.x;
  int stripe = bid & 3;
  int b = (bid >> 2) & 31;
  int l = bid >> 7;
  int t = threadIdx.x;
  int w = t >> 6, lane = t & 63;
  int n = lane & 15, q = lane >> 4;

  // zero LDS (halo stays zero), then stage interior rows once
  for (int i = t; i < 12 * 36 * CS / 2; i += 256) ((int*)hs)[i] = 0;
  __syncthreads();
  int y0 = stripe * 8;
  const short* hg = h1t + (size_t)(l * BATCH + b) * (HP * WP) * OC;
  {
    int col = t >> 3, icq = t & 7;
    for (int r = 0; r < 12; r++) {
      int y = y0 - 2 + r;
      if (y < 0 || y >= HP) continue;
      short8 v = *(const short8*)(hg + (y * WP + col) * OC + icq * 8);
      *(short8*)(&hs[r * RS + (col + 2) * CS + icq * 8]) = v;
    }
  }
  __syncthreads();

  f32x4 acc[4][4];  // [octile][pxtile]
#pragma unroll
  for (int i = 0; i < 4; i++)
#pragma unroll
    for (int j = 0; j < 4; j++) acc[i][j] = f32x4{0.f, 0.f, 0.f, 0.f};

  const short* wbase = wT + (size_t)l * 25 * OC * OC;
  short8 Acur[8], Anext[8];
#pragma unroll
  for (int oct = 0; oct < 4; oct++)
#pragma unroll
    for (int kk = 0; kk < 2; kk++)
      Anext[oct * 2 + kk] =
          *(const short8*)(wbase + (size_t)(oct * 16 + n) * OC + kk * 32 + q * 8);

  int prow = 2 * w;
  for (int tap = 0; tap < 25; tap++) {
#pragma unroll
    for (int i = 0; i < 8; i++) Acur[i] = Anext[i];
    if (tap < 24) {
      const short* tb = wbase + (size_t)(tap + 1) * OC * OC;
#pragma unroll
      for (int oct = 0; oct < 4; oct++)
#pragma unroll
        for (int kk = 0; kk < 2; kk++)
          Anext[oct * 2 + kk] =
              *(const short8*)(tb + (size_t)(oct * 16 + n) * OC + kk * 32 + q * 8);
    }
    int dy = tap / 5, dx = tap - 5 * dy;
#pragma unroll
    for (int pxt = 0; pxt < 4; pxt++) {
      int r = prow + (pxt >> 1) + dy;
      int c = (pxt & 1) * 16 + n + dx;
      const short* bp = &hs[r * RS + c * CS];
#pragma unroll
      for (int kk = 0; kk < 2; kk++) {
        short8 B = *(const short8*)(bp + kk * 32 + q * 8);
#pragma unroll
        for (int oct = 0; oct < 4; oct++)
          acc[oct][pxt] = __builtin_amdgcn_mfma_f32_16x16x32_bf16(
              Acur[oct * 2 + kk], B, acc[oct][pxt], 0, 0, 0);
      }
    }
  }

  // epilogue: max over this wave's 64 px; D layout: col(px)=lane&15, row(oc)=q*4+reg
#pragma unroll
  for (int oct = 0; oct < 4; oct++) {
    f32x4 m = acc[oct][0];
#pragma unroll
    for (int pxt = 1; pxt < 4; pxt++)
#pragma unroll
      for (int r = 0; r < 4; r++) m[r] = fmaxf(m[r], acc[oct][pxt][r]);
#pragma unroll
    for (int mask = 1; mask <= 8; mask <<= 1)
#pragma unroll
      for (int r = 0; r < 4; r++) m[r] = fmaxf(m[r], __shfl_xor(m[r], mask, 64));
    if (n == 0) *(f32x4*)&sred[w][oct * 16 + q * 4] = m;
  }
  __syncthreads();
  if (t < 64) {
    float m = fmaxf(fmaxf(sred[0][t], sred[1][t]), fmaxf(sred[2][t], sred[3][t]));
    pfeat[((size_t)(l * BATCH + b) * 4 + stripe) * OC + t] = m;
  }
}

// ---------------- per-leaf 2-layer MLP; folds stripe-max + relu ----------------
__global__ __launch_bounds__(128) void k_mlp(
    const float* __restrict__ pfeat, const float* __restrict__ w1s,
    const float* __restrict__ b1s, const float* __restrict__ w2s,
    const float* __restrict__ b2s, float* __restrict__ logits) {
  __shared__ float fs[OC];
  __shared__ float hid[LW];
  int bid = blockIdx.x;
  int b = bid & 31;
  int l = bid >> 5;
  int t = threadIdx.x;
  if (t < OC) {
    const float* pf = pfeat + (size_t)(l * BATCH + b) * 4 * OC;
    float m = fmaxf(fmaxf(pf[t], pf[OC + t]), fmaxf(pf[2 * OC + t], pf[3 * OC + t]));
    fs[t] = fmaxf(m, 0.f);  // relu(global max)
  }
  __syncthreads();
  float h = b1s[l * LW + t];
  for (int c = 0; c < OC; c++)
    h = fmaf(fs[c], w1s[(l * OC + c) * LW + t], h);
  hid[t] = h;
  __syncthreads();
  if (t < OW) {
    float o = b2s[l * OW + t];
    for (int j = 0; j < LW; j++)
      o = fmaf(hid[j], w2s[(l * LW + j) * OW + t], o);
    logits[(size_t)(l * BATCH + b) * OW + t] = o;
  }
}

// ---------------- out[b,o] = sum_l mix[b,l] * logits[l,b,o]  (fp32 out) ----------------
__global__ __launch_bounds__(256) void k_combine(
    const float* __restrict__ logits, const float* __restrict__ mix,
    float* __restrict__ out) {
  int idx = blockIdx.x * 256 + threadIdx.x;
  if (idx >= BATCH * OW) return;
  int b = idx / OW, o = idx - b * OW;
  float s = 0.f;
#pragma unroll
  for (int l = 0; l < NL; l++)
    s = fmaf(mix[b * NL + l], logits[((size_t)l * BATCH + b) * OW + o], s);
  out[idx] = s;
}

extern "C" void kernel_launch(void* const* d_in, const int* in_sizes, int n_in,
                              void* d_out, int out_size, void* d_ws, size_t ws_size,
                              hipStream_t stream) {
  const float* x   = (const float*)d_in[0];
  const float* nw  = (const float*)d_in[1];
  const float* nb  = (const float*)d_in[2];
  const float* cw1 = (const float*)d_in[3];
  const float* cw2 = (const float*)d_in[4];
  const float* w1s = (const float*)d_in[5];
  const float* b1s = (const float*)d_in[6];
  const float* w2s = (const float*)d_in[7];
  const float* b2s = (const float*)d_in[8];
  float* out = (float*)d_out;

  char* ws = (char*)d_ws;
  short* h1t = (short*)ws;  // [l,b][px 1024][ic 64] bf16 = 67.1 MB
  size_t off = (size_t)NL * BATCH * HP * WP * OC * sizeof(short);
  short* wT = (short*)(ws + off); off += (size_t)NL * 25 * OC * OC * sizeof(short);  // 3.28 MB
  short* wA = (short*)(ws + off); off += (size_t)NL * OC * 96 * sizeof(short);       // 196 KB
  float* scores = (float*)(ws + off); off += 4 * BATCH * sizeof(float);
  float* mixp   = (float*)(ws + off); off += BATCH * NL * sizeof(float);
  float* pfeat  = (float*)(ws + off); off += (size_t)NL * BATCH * 4 * OC * sizeof(float);
  float* logits = (float*)(ws + off); off += (size_t)NL * BATCH * OW * sizeof(float);
  (void)ws_size; (void)in_sizes; (void)n_in; (void)out_size;

  k_scores<<<4 * BATCH, 256, 0, stream>>>(x, nw, scores);
  k_mix<<<1, BATCH * NL, 0, stream>>>(scores, nb, mixp);
  k_w1prep<<<NL * OC * 96 / 256, 256, 0, stream>>>(cw1, wA);
  k_conv1m<<<BATCH * 32, 256, 0, stream>>>(x, wA, h1t);
  k_wprep<<<NL * 25 * OC * 8 / 256, 256, 0, stream>>>(cw2, wT);
  k_conv2m<<<NL * BATCH * 4, 256, 0, stream>>>(h1t, wT, pfeat);
  k_mlp<<<NL * BATCH, 128, 0, stream>>>(pfeat, w1s, b1s, w2s, b2s, logits);
  k_combine<<<(BATCH * OW + 255) / 256, 256, 0, stream>>>(logits, mixp, out);
}

// Round 6
// 432.021 us; speedup vs baseline: 5.0257x; 1.0334x over previous
//
#include <hip/hip_runtime.h>
#include <hip/hip_bf16.h>

using bf16 = __hip_bfloat16;
typedef __attribute__((ext_vector_type(8))) short short8;   // 8 bf16 (4 VGPR)
typedef __attribute__((ext_vector_type(4))) short short4v;  // 4 bf16 (8 B)
typedef __attribute__((ext_vector_type(4))) float f32x4;

constexpr int BATCH = 32;
constexpr int INC = 3;
constexpr int OC = 64;
constexpr int HH = 64;
constexpr int WW = 64;
constexpr int KK = 5;
constexpr int HP = 32;
constexpr int WP = 32;
constexpr int NL = 16;
constexpr int LW = 128;
constexpr int OW = 100;

__device__ __forceinline__ float b2f(bf16 v) { return __bfloat162float(v); }
__device__ __forceinline__ short f2bs(float v) {
  bf16 h = __float2bfloat16(v);
  return *(short*)&h;
}

// ---------------- routing scores: conv(x, node_filter) -> global max ----------------
__global__ __launch_bounds__(256) void k_scores(
    const float* __restrict__ x, const float* __restrict__ nw,
    float* __restrict__ scores) {
  int d = blockIdx.x & 3;
  int b = blockIdx.x >> 2;
  int f = (2 << d) - 2;  // node filter index used at depth d: 0,2,6,14
  __shared__ float wsm[75];
  __shared__ float red[256];
  int t = threadIdx.x;
  if (t < 75) wsm[t] = nw[f * 75 + t];
  __syncthreads();
  float m = -3.0e38f;
  for (int p = t; p < HH * WW; p += 256) {
    int y = p >> 6, xx = p & 63;
    float s = 0.f;
    for (int ic = 0; ic < INC; ic++) {
      for (int ky = 0; ky < KK; ky++) {
        int yy = y + ky - 2;
        if (yy < 0 || yy >= HH) continue;
        const float* xr = x + ((b * INC + ic) * HH + yy) * WW;
        const float* wr = &wsm[(ic * KK + ky) * KK];
        for (int kx = 0; kx < KK; kx++) {
          int xc = xx + kx - 2;
          if (xc < 0 || xc >= WW) continue;
          s = fmaf(xr[xc], wr[kx], s);
        }
      }
    }
    m = fmaxf(m, s);
  }
  red[t] = m;
  __syncthreads();
  for (int s2 = 128; s2 > 0; s2 >>= 1) {
    if (t < s2) red[t] = fmaxf(red[t], red[t + s2]);
    __syncthreads();
  }
  if (t == 0) scores[d * BATCH + b] = red[0];
}

// ---------------- soft-routing mixture over the binary tree ----------------
__global__ void k_mix(const float* __restrict__ scores,
                      const float* __restrict__ nb, float* __restrict__ mix) {
  int t = threadIdx.x;
  int b = t >> 4, l = t & 15;
  float m = 1.f;
#pragma unroll
  for (int d = 0; d < 4; d++) {
    int j = l >> (3 - d);
    int i = j >> 1;
    int bit = j & 1;
    float z = scores[d * BATCH + b] + nb[(1 << d) - 1 + i];
    float be = 1.f / (1.f + expf(-z));
    m *= bit ? be : (1.f - be);
  }
  mix[b * NL + l] = m;
}

// ---------------- merged weight prep ----------------
// blocks 0..383:   cw1[l*64+oc][75] fp32 -> wA[l][oc][96] bf16 (zero-pad K 75->96)
// blocks 384..1183: cw2[l][oc][ic][5][5] fp32 -> wT[l][tap][oc][ic] bf16
__global__ __launch_bounds__(256) void k_prep(
    const float* __restrict__ cw1, const float* __restrict__ cw2,
    short* __restrict__ wA, short* __restrict__ wT) {
  int idx = blockIdx.x * 256 + threadIdx.x;
  if (idx < 98304) {
    int k = idx % 96;
    int rem = idx / 96;  // l*64 + oc
    float v = (k < 75) ? cw1[(size_t)rem * 75 + k] : 0.f;
    wA[(size_t)rem * 96 + k] = f2bs(v);
  } else {
    int i2 = idx - 98304;  // < 204800
    int icq = i2 & 7;
    int oc = (i2 >> 3) & 63;
    int rem = i2 >> 9;  // l*25 + tap
    short8 v;
#pragma unroll
    for (int j = 0; j < 8; j++) {
      int ic = icq * 8 + j;
      int l = rem / 25, tap = rem % 25;
      v[j] = f2bs(cw2[((size_t)(l * OC + oc) * OC + ic) * 25 + tap]);
    }
    *(short8*)(wT + ((size_t)rem * OC + oc) * OC + icq * 8) = v;
  }
}

// ---------------- conv1 via im2col + MFMA + in-register maxpool/relu -> h1t ----------------
// grid: BATCH*32 blocks (b, pool-row py), 256 threads = 4 waves (wave = 16-oc group)
__device__ __forceinline__ int slotbase(int col) {
  return col * 104 + 8 * ((-(col >> 1)) & 7);
}

__global__ __launch_bounds__(256) void k_conv1m(
    const float* __restrict__ x, const short* __restrict__ wA,
    short* __restrict__ h1t) {
  constexpr int BSZ = 64 * 104 + 64;  // per-dy slab size in shorts
  constexpr int OTS = 72;             // out-tile stride (144B: 16B-aligned, 2-way banks)
  __shared__ alignas(16) short Bm[2 * BSZ];
  __shared__ alignas(16) short ot[32 * OTS];  // [px 32][oc 64(+pad)]
  int bid = blockIdx.x;
  int py = bid & 31;
  int b = bid >> 5;
  int t = threadIdx.x;
  int w = t >> 6, lane = t & 63;
  int n = lane & 15, q = lane >> 4;

  for (int i = t; i < BSZ; i += 256) ((int*)Bm)[i] = 0;
  __syncthreads();
  // im2col build: Bm[dy][c][k] = x[b][ic][2py+dy+ky-2][c+kx-2], k=(ic,ky,kx)
  for (int i = t; i < 1200; i += 256) {
    int cg = i & 7;
    int kk = (i >> 3) % 75;
    int dy = (i >> 3) / 75;
    int ic = kk / 25, r25 = kk % 25;
    int ky = r25 / 5, kx = r25 % 5;
    int y = 2 * py + dy + ky - 2;
    const float* xr = x + ((size_t)(b * INC + ic) * HH + y) * WW;
    short* dst = Bm + dy * BSZ;
#pragma unroll
    for (int c8 = 0; c8 < 8; c8++) {
      int c = cg * 8 + c8;
      int cx = c + kx - 2;
      float v = 0.f;
      if (y >= 0 && y < HH && cx >= 0 && cx < WW) v = xr[cx];
      dst[slotbase(c) + kk] = f2bs(v);
    }
  }
  __syncthreads();

  short8 Acur[3], Anx[3];
#pragma unroll
  for (int ks = 0; ks < 3; ks++)
    Anx[ks] = *(const short8*)(wA + ((size_t)(w * 16 + n) * 96) + ks * 32 + q * 8);

  for (int l = 0; l < NL; l++) {
#pragma unroll
    for (int ks = 0; ks < 3; ks++) Acur[ks] = Anx[ks];
    if (l < NL - 1) {
#pragma unroll
      for (int ks = 0; ks < 3; ks++)
        Anx[ks] = *(const short8*)(wA + ((size_t)((l + 1) * OC + w * 16 + n) * 96) +
                                   ks * 32 + q * 8);
    }
    f32x4 acc[2][2][2];  // [dy][dx][half]
#pragma unroll
    for (int dy = 0; dy < 2; dy++)
#pragma unroll
      for (int dx = 0; dx < 2; dx++)
#pragma unroll
        for (int h = 0; h < 2; h++) acc[dy][dx][h] = f32x4{0.f, 0.f, 0.f, 0.f};

#pragma unroll
    for (int dy = 0; dy < 2; dy++)
#pragma unroll
      for (int dx = 0; dx < 2; dx++)
#pragma unroll
        for (int h = 0; h < 2; h++) {
          int col = 2 * (h * 16 + n) + dx;
          const short* bp = Bm + dy * BSZ + slotbase(col);
#pragma unroll
          for (int ks = 0; ks < 3; ks++) {
            short8 Bf = *(const short8*)(bp + ks * 32 + q * 8);
            acc[dy][dx][h] = __builtin_amdgcn_mfma_f32_16x16x32_bf16(
                Acur[ks], Bf, acc[dy][dx][h], 0, 0, 0);
          }
        }

    // pool over (dy,dx), relu -> LDS tile (conflict-free), then coalesced 16B stores
#pragma unroll
    for (int h = 0; h < 2; h++) {
      short4v sv;
#pragma unroll
      for (int r = 0; r < 4; r++) {
        float v = fmaxf(fmaxf(acc[0][0][h][r], acc[0][1][h][r]),
                        fmaxf(acc[1][0][h][r], acc[1][1][h][r]));
        sv[r] = f2bs(fmaxf(v, 0.f));
      }
      *(short4v*)(&ot[(h * 16 + n) * OTS + w * 16 + q * 4]) = sv;
    }
    __syncthreads();
    {
      int px = t >> 3, seg = t & 7;  // 32 px x 8 segs = 256
      short8 v = *(const short8*)(&ot[px * OTS + seg * 8]);
      *(short8*)(h1t + ((size_t)(l * BATCH + b) * (HP * WP) + py * WP + px) * OC +
                 seg * 8) = v;
    }
    __syncthreads();
  }
}

// ---------------- conv2 via MFMA implicit GEMM (2 ic-chunks) + spatial max -> pfeat -------
// grid: NL*BATCH*4 blocks (l, b, 8-row stripe), 256 threads = 4 waves
// LDS slab per chunk: [12 rows][36 cols][32 ic + 4 pad] bf16 = 34.6 KB -> 4 blocks/CU.
__global__ __launch_bounds__(256) void k_conv2m(
    const short* __restrict__ h1t, const short* __restrict__ wT,
    float* __restrict__ pfeat) {
  constexpr int CS = 40;        // 80 B: 16B-aligned; 20n mod 32 -> 2-way (free)
  constexpr int RS = 36 * CS;
  __shared__ alignas(16) short hs[12 * RS];  // 34,560 B
  __shared__ alignas(16) float sred[4][64];
  int bid = blockIdx.x;
  int stripe = bid & 3;
  int b = (bid >> 2) & 31;
  int l = bid >> 7;
  int t = threadIdx.x;
  int w = t >> 6, lane = t & 63;
  int n = lane & 15, q = lane >> 4;
  int y0 = stripe * 8;
  const short* hg = h1t + (size_t)(l * BATCH + b) * (HP * WP) * OC;
  const short* wbase = wT + (size_t)l * 25 * OC * OC;

  f32x4 acc[4][4];  // [octile][pxtile]
#pragma unroll
  for (int i = 0; i < 4; i++)
#pragma unroll
    for (int j = 0; j < 4; j++) acc[i][j] = f32x4{0.f, 0.f, 0.f, 0.f};

  short8 Acur[4], Anext[4];
  // A-frag: A[m=lane&15][k=q*8+j]; k = ic within current 32-chunk
#pragma unroll
  for (int oct = 0; oct < 4; oct++)
    Anext[oct] = *(const short8*)(wbase + (size_t)(oct * 16 + n) * OC + q * 8);

  int prow = 2 * w;
  for (int chunk = 0; chunk < 2; chunk++) {
    __syncthreads();  // protect hs from previous chunk's readers
    // stage with predication (halo written as zeros): 12r x 36c x 4 icq = 1728 short8
    for (int idx = t; idx < 12 * 36 * 4; idx += 256) {
      int icq = idx & 3;
      int c = (idx >> 2) % 36;
      int r = (idx >> 2) / 36;
      int y = y0 - 2 + r, xx = c - 2;
      short8 v = short8{0, 0, 0, 0, 0, 0, 0, 0};
      if (y >= 0 && y < HP && xx >= 0 && xx < WP)
        v = *(const short8*)(hg + (y * WP + xx) * OC + chunk * 32 + icq * 8);
      *(short8*)(&hs[r * RS + c * CS + icq * 8]) = v;
    }
    __syncthreads();
    for (int tap = 0; tap < 25; tap++) {
#pragma unroll
      for (int i = 0; i < 4; i++) Acur[i] = Anext[i];
      if (!(chunk == 1 && tap == 24)) {
        int ntap = tap + 1, nchunk = chunk;
        if (ntap == 25) { ntap = 0; nchunk = 1; }
        const short* tb = wbase + (size_t)ntap * OC * OC;
#pragma unroll
        for (int oct = 0; oct < 4; oct++)
          Anext[oct] = *(const short8*)(tb + (size_t)(oct * 16 + n) * OC +
                                        nchunk * 32 + q * 8);
      }
      int dy = tap / 5, dx = tap - 5 * dy;
#pragma unroll
      for (int pxt = 0; pxt < 4; pxt++) {
        int r = prow + (pxt >> 1) + dy;
        int c = (pxt & 1) * 16 + n + dx;
        short8 B = *(const short8*)(&hs[r * RS + c * CS + q * 8]);
#pragma unroll
        for (int oct = 0; oct < 4; oct++)
          acc[oct][pxt] = __builtin_amdgcn_mfma_f32_16x16x32_bf16(
              Acur[oct], B, acc[oct][pxt], 0, 0, 0);
      }
    }
  }

  // epilogue: max over this wave's 64 px; D layout: col(px)=lane&15, row(oc)=q*4+reg
#pragma unroll
  for (int oct = 0; oct < 4; oct++) {
    f32x4 m = acc[oct][0];
#pragma unroll
    for (int pxt = 1; pxt < 4; pxt++)
#pragma unroll
      for (int r = 0; r < 4; r++) m[r] = fmaxf(m[r], acc[oct][pxt][r]);
#pragma unroll
    for (int mask = 1; mask <= 8; mask <<= 1)
#pragma unroll
      for (int r = 0; r < 4; r++) m[r] = fmaxf(m[r], __shfl_xor(m[r], mask, 64));
    if (n == 0) *(f32x4*)&sred[w][oct * 16 + q * 4] = m;
  }
  __syncthreads();
  if (t < 64) {
    float m = fmaxf(fmaxf(sred[0][t], sred[1][t]), fmaxf(sred[2][t], sred[3][t]));
    pfeat[((size_t)(l * BATCH + b) * 4 + stripe) * OC + t] = m;
  }
}

// ---------------- per-leaf 2-layer MLP; folds stripe-max + relu ----------------
__global__ __launch_bounds__(128) void k_mlp(
    const float* __restrict__ pfeat, const float* __restrict__ w1s,
    const float* __restrict__ b1s, const float* __restrict__ w2s,
    const float* __restrict__ b2s, float* __restrict__ logits) {
  __shared__ float fs[OC];
  __shared__ float hid[LW];
  int bid = blockIdx.x;
  int b = bid & 31;
  int l = bid >> 5;
  int t = threadIdx.x;
  if (t < OC) {
    const float* pf = pfeat + (size_t)(l * BATCH + b) * 4 * OC;
    float m = fmaxf(fmaxf(pf[t], pf[OC + t]), fmaxf(pf[2 * OC + t], pf[3 * OC + t]));
    fs[t] = fmaxf(m, 0.f);  // relu(global max)
  }
  __syncthreads();
  float h = b1s[l * LW + t];
  for (int c = 0; c < OC; c++)
    h = fmaf(fs[c], w1s[(l * OC + c) * LW + t], h);
  hid[t] = h;
  __syncthreads();
  if (t < OW) {
    float o = b2s[l * OW + t];
    for (int j = 0; j < LW; j++)
      o = fmaf(hid[j], w2s[(l * LW + j) * OW + t], o);
    logits[(size_t)(l * BATCH + b) * OW + t] = o;
  }
}

// ---------------- out[b,o] = sum_l mix[b,l] * logits[l,b,o]  (fp32 out) ----------------
__global__ __launch_bounds__(256) void k_combine(
    const float* __restrict__ logits, const float* __restrict__ mix,
    float* __restrict__ out) {
  int idx = blockIdx.x * 256 + threadIdx.x;
  if (idx >= BATCH * OW) return;
  int b = idx / OW, o = idx - b * OW;
  float s = 0.f;
#pragma unroll
  for (int l = 0; l < NL; l++)
    s = fmaf(mix[b * NL + l], logits[((size_t)l * BATCH + b) * OW + o], s);
  out[idx] = s;
}

extern "C" void kernel_launch(void* const* d_in, const int* in_sizes, int n_in,
                              void* d_out, int out_size, void* d_ws, size_t ws_size,
                              hipStream_t stream) {
  const float* x   = (const float*)d_in[0];
  const float* nw  = (const float*)d_in[1];
  const float* nb  = (const float*)d_in[2];
  const float* cw1 = (const float*)d_in[3];
  const float* cw2 = (const float*)d_in[4];
  const float* w1s = (const float*)d_in[5];
  const float* b1s = (const float*)d_in[6];
  const float* w2s = (const float*)d_in[7];
  const float* b2s = (const float*)d_in[8];
  float* out = (float*)d_out;

  char* ws = (char*)d_ws;
  short* h1t = (short*)ws;  // [l,b][px 1024][ic 64] bf16 = 67.1 MB
  size_t off = (size_t)NL * BATCH * HP * WP * OC * sizeof(short);
  short* wT = (short*)(ws + off); off += (size_t)NL * 25 * OC * OC * sizeof(short);  // 3.28 MB
  short* wA = (short*)(ws + off); off += (size_t)NL * OC * 96 * sizeof(short);       // 196 KB
  float* scores = (float*)(ws + off); off += 4 * BATCH * sizeof(float);
  float* mixp   = (float*)(ws + off); off += BATCH * NL * sizeof(float);
  float* pfeat  = (float*)(ws + off); off += (size_t)NL * BATCH * 4 * OC * sizeof(float);
  float* logits = (float*)(ws + off); off += (size_t)NL * BATCH * OW * sizeof(float);
  (void)ws_size; (void)in_sizes; (void)n_in; (void)out_size;

  k_scores<<<4 * BATCH, 256, 0, stream>>>(x, nw, scores);
  k_mix<<<1, BATCH * NL, 0, stream>>>(scores, nb, mixp);
  k_prep<<<(98304 + 204800) / 256, 256, 0, stream>>>(cw1, cw2, wA, wT);
  k_conv1m<<<BATCH * 32, 256, 0, stream>>>(x, wA, h1t);
  k_conv2m<<<NL * BATCH * 4, 256, 0, stream>>>(h1t, wT, pfeat);
  k_mlp<<<NL * BATCH, 128, 0, stream>>>(pfeat, w1s, b1s, w2s, b2s, logits);
  k_combine<<<(BATCH * OW + 255) / 256, 256, 0, stream>>>(logits, mixp, out);
}